// Round 5
// baseline (303.195 us; speedup 1.0000x reference)
//
#include <hip/hip_runtime.h>

// ---------------------------------------------------------------------------
// GCN: out = A_norm * relu(A_norm * X * W1 + b1) * W2 + b2
// A_norm = D^-1/2 (A + I) D^-1/2, built from 1.6M random edges + self loops.
//
// Round-5 change: k_count's 1.6M device-scope far atomics (22.5 G/s wall,
// 56 MB of 32B-sector writebacks) replaced by LDS-privatized per-block
// histograms (k_hist: local rank via LDS atomics on packed 16-bit counters,
// 50KB LDS, two half-range passes) + a column scan over per-block counts
// (k_colscan) that yields per-(block,node) base offsets in place.
// ---------------------------------------------------------------------------

#define SCAN_TILE 2048   // 256 threads x 8 elements
#define EPB_LOG 14
#define EPB (1 << EPB_LOG)     // 16384 edges per histogram block
#define HALF 25024             // dst range covered per LDS pass
#define BINS_U32 12512         // HALF/2 packed dual-ushort counters
#define MAXN_FAST (2 * HALF)   // 50048

typedef __attribute__((ext_vector_type(8))) short bf16x8;
typedef __attribute__((ext_vector_type(4))) float f32x4;

__device__ inline unsigned short f2bf(float f) {
    unsigned int b = __float_as_uint(f);
    unsigned int r = b + 0x7FFFu + ((b >> 16) & 1u);   // round-to-nearest-even
    return (unsigned short)(r >> 16);
}
__device__ inline float bf_lo(unsigned int u) { return __uint_as_float(u << 16); }
__device__ inline float bf_hi(unsigned int u) { return __uint_as_float(u & 0xFFFF0000u); }

__global__ void k_init(const int* __restrict__ edges, int* __restrict__ flag,
                       int* __restrict__ cnt, int n) {
    int i = blockIdx.x * blockDim.x + threadIdx.x;
    if (i < n) cnt[i] = 0;   // only needed by the fallback path; cheap
    if (blockIdx.x == 0 && threadIdx.x < 64) {
        // int64 edges little-endian -> odd 32-bit words all zero (vals < 50000)
        int v = edges[2 * threadIdx.x + 1];
        unsigned long long b = __ballot(v != 0);
        if (threadIdx.x == 0) flag[0] = b ? 1 : 2;   // stride in int32 words
    }
}

// x (fp32) -> xh (bf16), 4 elems/thread
__global__ __launch_bounds__(256) void k_prep_x(const float* __restrict__ x,
        unsigned short* __restrict__ xh, int total4) {
    int i = blockIdx.x * 256 + threadIdx.x;
    if (i >= total4) return;
    float4 v = *(const float4*)(x + (size_t)i * 4);
    ushort4 o;
    o.x = f2bf(v.x); o.y = f2bf(v.y); o.z = f2bf(v.z); o.w = f2bf(v.w);
    *(ushort4*)(xh + (size_t)i * 4) = o;
}

// W1 [128][256] fp32 -> W1t [256][128] bf16.
__global__ __launch_bounds__(128) void k_prep_w(const float* __restrict__ W1,
        unsigned short* __restrict__ w1t) {
    int n = blockIdx.x;          // 0..255
    int k = threadIdx.x;         // 0..127
    w1t[n * 128 + k] = f2bf(W1[k * 256 + n]);
}

// Per-block LDS histogram + local rank. Block b owns edges [b*EPB, b*EPB+EPB).
// Packed dual 16-bit counters: bins[r>>1], halves indexed by r&1. Counts per
// (block,dst) <= EPB < 65536 so the low half can never carry into the high.
__global__ __launch_bounds__(256) void k_hist(
        const int* __restrict__ edges, const int* __restrict__ flag,
        unsigned int* __restrict__ hist_u32,   // [nb][n/2] packed ushort pairs
        unsigned short* __restrict__ pos, long long E, int n) {
    __shared__ unsigned int bins[BINS_U32];    // 50 KB
    int b = blockIdx.x, t = threadIdx.x;
    int stride = flag[0];
    long long base = (long long)b << EPB_LOG;
    long long rem = E - base;
    int nE = (rem < (long long)EPB) ? (int)rem : EPB;
#pragma unroll 1
    for (int p = 0; p < 2; ++p) {
        for (int i = t; i < BINS_U32; i += 256) bins[i] = 0;
        __syncthreads();
        int dbase = p * HALF;
        for (int i = t; i < nE; i += 256) {
            int d = edges[(E + base + i) * stride];
            unsigned int r = (unsigned int)(d - dbase);
            if (r < (unsigned int)HALF) {
                unsigned int sh = (r & 1u) * 16u;
                unsigned int old = atomicAdd(&bins[r >> 1], 1u << sh);
                pos[base + i] = (unsigned short)((old >> sh) & 0xFFFFu);
            }
        }
        __syncthreads();
        unsigned int* dstrow = hist_u32 + (size_t)b * (n >> 1) + p * BINS_U32;
        int lim = (n >> 1) - p * BINS_U32;
        if (lim > BINS_U32) lim = BINS_U32;
        for (int i = t; i < lim; i += 256) dstrow[i] = bins[i];
        __syncthreads();
    }
}

// Column scan over per-block counts: hist[b][i] (count) -> hist[b][i]
// (exclusive offset of block b within node i's CSR row); cnt[i] = total.
__global__ __launch_bounds__(256) void k_colscan(
        unsigned short* __restrict__ hist, int* __restrict__ cnt, int nb, int n) {
    int i = blockIdx.x * 256 + threadIdx.x;
    if (i >= n) return;
    int run = 0;
    size_t idx = i;
    for (int b = 0; b < nb; ++b, idx += n) {
        int v = hist[idx];
        hist[idx] = (unsigned short)run;
        run += v;
    }
    cnt[i] = run;
}

// Per-block sums of cnt (8 elems/thread).
__global__ __launch_bounds__(256) void k_scan_partial(
        const int* __restrict__ cnt, int* __restrict__ bsum, int n) {
    int t = threadIdx.x;
    int idx = blockIdx.x * SCAN_TILE + t * 8;
    int s = 0;
#pragma unroll
    for (int j = 0; j < 8; ++j) {
        int i = idx + j;
        if (i < n) s += cnt[i];
    }
    for (int off = 32; off; off >>= 1) s += __shfl_down(s, off, 64);
    __shared__ int ws[4];
    if ((t & 63) == 0) ws[t >> 6] = s;
    __syncthreads();
    if (t == 0) bsum[blockIdx.x] = ws[0] + ws[1] + ws[2] + ws[3];
}

// Exclusive scan of <=64 block sums, in place, one wave.
__global__ void k_scan_tops(int* __restrict__ bsum, int nb) {
    int t = threadIdx.x;
    int w = (t < nb) ? bsum[t] : 0;
    int v = w;
    for (int off = 1; off < 64; off <<= 1) {
        int u = __shfl_up(v, off, 64);
        if (t >= off) v += u;
    }
    if (t < nb) bsum[t] = v - w;   // exclusive
}

// Apply: recompute intra-block prefix, add block offset, emit row_start & dis.
__global__ __launch_bounds__(256) void k_scan_apply(
        const int* __restrict__ cnt, const int* __restrict__ bsum,
        int* __restrict__ row_start, float* __restrict__ dis, int n) {
    int t = threadIdx.x;
    int lane = t & 63, w = t >> 6;
    int idx = blockIdx.x * SCAN_TILE + t * 8;
    int vals[8];
    int s = 0;
#pragma unroll
    for (int j = 0; j < 8; ++j) {
        int i = idx + j;
        vals[j] = (i < n) ? cnt[i] : 0;
        s += vals[j];
    }
    int inc = s;
    for (int off = 1; off < 64; off <<= 1) {
        int u = __shfl_up(inc, off, 64);
        if (lane >= off) inc += u;
    }
    __shared__ int wsum[4];
    if (lane == 63) wsum[w] = inc;
    __syncthreads();
    int woff = 0;
    for (int i = 0; i < w; ++i) woff += wsum[i];
    int ex = bsum[blockIdx.x] + woff + inc - s;  // exclusive prefix of this chunk
#pragma unroll
    for (int j = 0; j < 8; ++j) {
        int i = idx + j;
        if (i < n) {
            row_start[i] = ex;
            dis[i] = rsqrtf((float)vals[j] + 1.0f);  // +1 = self loop
            ex += vals[j];
        }
    }
    if (idx <= n && n < idx + 8) row_start[n] = ex;  // unique thread
}

// csr_src[rs[d] + boff[b][d] + pos[e]] = s. No atomics.
__global__ void k_scatter(const int* __restrict__ edges, const int* __restrict__ flag,
                          const int* __restrict__ row_start,
                          const unsigned short* __restrict__ boff,
                          const unsigned short* __restrict__ pos,
                          int* __restrict__ csr_src, long long E, int n) {
    long long e = (long long)blockIdx.x * blockDim.x + threadIdx.x;
    if (e >= E) return;
    int stride = flag[0];
    int s = edges[e * stride];
    int d = edges[(E + e) * stride];
    int b = (int)(e >> EPB_LOG);
    int j = row_start[d] + (int)boff[(size_t)b * n + d] + (int)pos[e];
    csr_src[j] = s;
}

// ---- fallback path (only if n odd or n > 50048; never for this problem) ----
__global__ void k_count_slow(const int* __restrict__ edges, const int* __restrict__ flag,
                             int* __restrict__ cnt, int* __restrict__ posi, long long E) {
    long long e = (long long)blockIdx.x * blockDim.x + threadIdx.x;
    if (e >= E) return;
    int stride = flag[0];
    int d = edges[(E + e) * stride];
    posi[e] = atomicAdd(&cnt[d], 1);
}
__global__ void k_scatter_slow(const int* __restrict__ edges, const int* __restrict__ flag,
                               const int* __restrict__ row_start, const int* __restrict__ posi,
                               int* __restrict__ csr_src, long long E) {
    long long e = (long long)blockIdx.x * blockDim.x + threadIdx.x;
    if (e >= E) return;
    int stride = flag[0];
    int s = edges[e * stride];
    int d = edges[(E + e) * stride];
    csr_src[row_start[d] + posi[e]] = s;
}
// ---------------------------------------------------------------------------

// One wave per node; lane owns features {2*lane, 2*lane+1} (one uint = 2 bf16).
__global__ __launch_bounds__(256) void k_agg(
        const unsigned short* __restrict__ xh, const int* __restrict__ csr_src,
        const int* __restrict__ row_start, const float* __restrict__ dis,
        unsigned short* __restrict__ aggh, int n) {
    int wid  = (blockIdx.x * blockDim.x + threadIdx.x) >> 6;
    int lane = threadIdx.x & 63;
    if (wid >= n) return;
    int start = row_start[wid], end = row_start[wid + 1];
    float dn = dis[wid];
    unsigned int self = ((const unsigned int*)(xh + (size_t)wid * 128))[lane];
    float acc0 = dn * dn * bf_lo(self);
    float acc1 = dn * dn * bf_hi(self);
    int e = start;
    for (; e + 3 < end; e += 4) {
        int s0 = csr_src[e],     s1 = csr_src[e + 1];
        int s2 = csr_src[e + 2], s3 = csr_src[e + 3];
        float n0 = dis[s0] * dn, n1 = dis[s1] * dn;
        float n2 = dis[s2] * dn, n3 = dis[s3] * dn;
        unsigned int v0 = ((const unsigned int*)(xh + (size_t)s0 * 128))[lane];
        unsigned int v1 = ((const unsigned int*)(xh + (size_t)s1 * 128))[lane];
        unsigned int v2 = ((const unsigned int*)(xh + (size_t)s2 * 128))[lane];
        unsigned int v3 = ((const unsigned int*)(xh + (size_t)s3 * 128))[lane];
        acc0 += n0 * bf_lo(v0); acc1 += n0 * bf_hi(v0);
        acc0 += n1 * bf_lo(v1); acc1 += n1 * bf_hi(v1);
        acc0 += n2 * bf_lo(v2); acc1 += n2 * bf_hi(v2);
        acc0 += n3 * bf_lo(v3); acc1 += n3 * bf_hi(v3);
    }
    for (; e < end; ++e) {
        int s0 = csr_src[e];
        float n0 = dis[s0] * dn;
        unsigned int v0 = ((const unsigned int*)(xh + (size_t)s0 * 128))[lane];
        acc0 += n0 * bf_lo(v0); acc1 += n0 * bf_hi(v0);
    }
    unsigned int pack = (unsigned int)f2bf(acc0) | ((unsigned int)f2bf(acc1) << 16);
    ((unsigned int*)(aggh + (size_t)wid * 128))[lane] = pack;
}

// MFMA GEMM: sv = relu(agg @ W1 + b1) @ W2.
__global__ __launch_bounds__(256) void k_mm(
        const unsigned short* __restrict__ aggh, const unsigned short* __restrict__ w1t,
        const float* __restrict__ b1, const float* __restrict__ W2,
        float* __restrict__ sv, int n) {
    int wave = threadIdx.x >> 6;        // 0..3
    int lane = threadIdx.x & 63;
    int m    = lane & 15;
    int quad = lane >> 4;               // 0..3
    int node0 = blockIdx.x * 64 + wave * 16;

    bf16x8 afrag[4];
    const unsigned short* arow = aggh + (size_t)(node0 + m) * 128 + quad * 8;
#pragma unroll
    for (int ks = 0; ks < 4; ++ks)
        afrag[ks] = *(const bf16x8*)(arow + ks * 32);

    float p0 = 0.f, p1 = 0.f, p2 = 0.f, p3 = 0.f;
#pragma unroll 1
    for (int t = 0; t < 16; ++t) {
        const unsigned short* brow = w1t + (size_t)(t * 16 + m) * 128 + quad * 8;
        f32x4 acc = {0.f, 0.f, 0.f, 0.f};
#pragma unroll
        for (int ks = 0; ks < 4; ++ks) {
            bf16x8 bfrag = *(const bf16x8*)(brow + ks * 32);
            acc = __builtin_amdgcn_mfma_f32_16x16x32_bf16(afrag[ks], bfrag, acc, 0, 0, 0);
        }
        int col = t * 16 + m;
        float bb = b1[col], w2 = W2[col];
        float h0 = acc[0] + bb, h1 = acc[1] + bb, h2 = acc[2] + bb, h3 = acc[3] + bb;
        p0 += (h0 > 0.f ? h0 : 0.f) * w2;
        p1 += (h1 > 0.f ? h1 : 0.f) * w2;
        p2 += (h2 > 0.f ? h2 : 0.f) * w2;
        p3 += (h3 > 0.f ? h3 : 0.f) * w2;
    }
#pragma unroll
    for (int off = 1; off < 16; off <<= 1) {
        p0 += __shfl_xor(p0, off, 64);
        p1 += __shfl_xor(p1, off, 64);
        p2 += __shfl_xor(p2, off, 64);
        p3 += __shfl_xor(p3, off, 64);
    }
    if (m == 0) {
        int nb = node0 + quad * 4;
        if (nb + 0 < n) sv[nb + 0] = p0;
        if (nb + 1 < n) sv[nb + 1] = p1;
        if (nb + 2 < n) sv[nb + 2] = p2;
        if (nb + 3 < n) sv[nb + 3] = p3;
    }
}

// out[i] = b2 + dis_i * (dis_i * s[i] + sum_e dis[src] * s[src]); wave per node.
__global__ __launch_bounds__(256) void k_out(
        const float* __restrict__ sv, const int* __restrict__ csr_src,
        const int* __restrict__ row_start, const float* __restrict__ dis,
        const float* __restrict__ b2, float* __restrict__ out, int n) {
    int wid  = (blockIdx.x * blockDim.x + threadIdx.x) >> 6;
    int lane = threadIdx.x & 63;
    if (wid >= n) return;
    int start = row_start[wid], end = row_start[wid + 1];
    float dn = dis[wid];
    float acc = 0.f;
    for (int e = start + lane; e < end; e += 64) {
        int s = csr_src[e];
        acc += dis[s] * sv[s];
    }
    for (int off = 32; off; off >>= 1) acc += __shfl_down(acc, off, 64);
    if (lane == 0)
        out[wid] = dn * (acc + dn * sv[wid]) + b2[0];
}

extern "C" void kernel_launch(void* const* d_in, const int* in_sizes, int n_in,
                              void* d_out, int out_size, void* d_ws, size_t ws_size,
                              hipStream_t stream) {
    const float* x  = (const float*)d_in[0];
    const int*   ei = (const int*)d_in[1];
    const float* W1 = (const float*)d_in[2];
    const float* b1 = (const float*)d_in[3];
    const float* W2 = (const float*)d_in[4];
    const float* b2 = (const float*)d_in[5];
    float* out = (float*)d_out;

    const int N = in_sizes[0] / 128;
    const long long E = in_sizes[1] / 2;
    const int nb_c = (int)((E + EPB - 1) >> EPB_LOG);   // 98 histogram blocks

    char* ws = (char*)d_ws;
    size_t off = 0;
    auto take = [&](size_t bytes) -> char* {
        char* p = ws + off;
        off = (off + bytes + 255) & ~(size_t)255;
        return p;
    };
    int*            flag    = (int*)take(4);
    int*            cnt     = (int*)take((size_t)N * 4);
    int*            rs      = (int*)take((size_t)(N + 1) * 4);
    float*          dis     = (float*)take((size_t)N * 4);
    float*          sv      = (float*)take((size_t)N * 4);
    int*            bsum    = (int*)take(64 * 4);
    char*           posb    = take((size_t)E * 4);        // ushort fast / int slow
    int*            csr_src = (int*)take((size_t)E * 4);
    unsigned short* xh      = (unsigned short*)take((size_t)N * 128 * 2);
    unsigned short* w1t     = (unsigned short*)take((size_t)256 * 128 * 2);
    unsigned short* aggh    = (unsigned short*)take((size_t)(N + 64) * 128 * 2);
    unsigned short* hist    = (unsigned short*)take((size_t)nb_c * (N + 2) * 2);

    int nb_n  = (N + 255) / 256;
    int nb_e  = (int)((E + 255) / 256);
    int nb_s  = (N + SCAN_TILE - 1) / SCAN_TILE;   // 25 for N=50000
    int nb_x  = (N * 128 / 4 + 255) / 256;
    int nb_mm = (N + 63) / 64;

    bool fast = ((N & 1) == 0) && (N <= MAXN_FAST);

    k_init   <<<nb_n, 256, 0, stream>>>(ei, flag, cnt, N);
    k_prep_x <<<nb_x, 256, 0, stream>>>(x, xh, N * 128 / 4);
    k_prep_w <<<256, 128, 0, stream>>>(W1, w1t);
    if (fast) {
        k_hist   <<<nb_c, 256, 0, stream>>>(ei, flag, (unsigned int*)hist,
                                            (unsigned short*)posb, E, N);
        k_colscan<<<nb_n, 256, 0, stream>>>(hist, cnt, nb_c, N);
    } else {
        k_count_slow<<<nb_e, 256, 0, stream>>>(ei, flag, cnt, (int*)posb, E);
    }
    k_scan_partial<<<nb_s, 256, 0, stream>>>(cnt, bsum, N);
    k_scan_tops   <<<1, 64, 0, stream>>>(bsum, nb_s);
    k_scan_apply  <<<nb_s, 256, 0, stream>>>(cnt, bsum, rs, dis, N);
    if (fast) {
        k_scatter<<<nb_e, 256, 0, stream>>>(ei, flag, rs, hist,
                                            (const unsigned short*)posb, csr_src, E, N);
    } else {
        k_scatter_slow<<<nb_e, 256, 0, stream>>>(ei, flag, rs, (const int*)posb, csr_src, E);
    }
    k_agg<<<(N + 3) / 4, 256, 0, stream>>>(xh, csr_src, rs, dis, aggh, N);
    k_mm <<<nb_mm, 256, 0, stream>>>(aggh, w1t, b1, W2, sv, N);
    k_out<<<(N + 3) / 4, 256, 0, stream>>>(sv, csr_src, rs, dis, b2, out, N);
}

// Round 6
// 278.956 us; speedup vs baseline: 1.0869x; 1.0869x over previous
//
#include <hip/hip_runtime.h>

// ---------------------------------------------------------------------------
// GCN: out = A_norm * relu(A_norm * X * W1 + b1) * W2 + b2
// A_norm = D^-1/2 (A + I) D^-1/2, built from 1.6M random edges + self loops.
//
// Round-6 changes:
//  * k_hist re-gridded: (superblock of 16384 edges) x (4 dst-range quarters)
//    -> 392 blocks @ 25KB LDS (6 blocks/CU) instead of 98 @ 50KB (<1/CU).
//  * x pre-scaled by dis in the bf16 cast (k_prep_xs, post-scan):
//    agg_i = dn_i*(sum xs[src] + xs_i) -- kills the 1.6M random dis[s] loads
//    and per-edge multiply in k_agg. k_mm stores svs = dis*sv so k_out's
//    dis gather disappears the same way.
//  * k_agg: 8-edge unroll (8 independent 256B row gathers in flight).
// ---------------------------------------------------------------------------

#define SCAN_TILE 2048   // 256 threads x 8 elements
#define EPB_LOG 14
#define EPB (1 << EPB_LOG)     // 16384 edges per superblock
#define NQ 4                   // dst-range quarters per superblock
#define QR 12512               // dst range per quarter (even)
#define QBINS (QR / 2)         // packed dual-ushort counters -> 25 KB LDS
#define MAXN_FAST (NQ * QR)    // 50048

typedef __attribute__((ext_vector_type(8))) short bf16x8;
typedef __attribute__((ext_vector_type(4))) float f32x4;

__device__ inline unsigned short f2bf(float f) {
    unsigned int b = __float_as_uint(f);
    unsigned int r = b + 0x7FFFu + ((b >> 16) & 1u);   // round-to-nearest-even
    return (unsigned short)(r >> 16);
}
__device__ inline float bf_lo(unsigned int u) { return __uint_as_float(u << 16); }
__device__ inline float bf_hi(unsigned int u) { return __uint_as_float(u & 0xFFFF0000u); }

__global__ void k_init(const int* __restrict__ edges, int* __restrict__ flag,
                       int* __restrict__ cnt, int n) {
    int i = blockIdx.x * blockDim.x + threadIdx.x;
    if (i < n) cnt[i] = 0;   // needed by the fallback path only; cheap
    if (blockIdx.x == 0 && threadIdx.x < 64) {
        // int64 edges little-endian -> odd 32-bit words all zero (vals < 50000)
        int v = edges[2 * threadIdx.x + 1];
        unsigned long long b = __ballot(v != 0);
        if (threadIdx.x == 0) flag[0] = b ? 1 : 2;   // stride in int32 words
    }
}

// W1 [128][256] fp32 -> W1t [256][128] bf16.
__global__ __launch_bounds__(128) void k_prep_w(const float* __restrict__ W1,
        unsigned short* __restrict__ w1t) {
    int n = blockIdx.x;          // 0..255
    int k = threadIdx.x;         // 0..127
    w1t[n * 128 + k] = f2bf(W1[k * 256 + n]);
}

// xs = bf16(dis[node] * x) -- runs AFTER the scan produced dis.
__global__ __launch_bounds__(256) void k_prep_xs(const float* __restrict__ x,
        const float* __restrict__ dis, unsigned short* __restrict__ xs, int n) {
    int i = blockIdx.x * 256 + threadIdx.x;      // over n*32 float4 groups
    if (i >= n * 32) return;
    float dsc = dis[i >> 5];
    float4 v = ((const float4*)x)[i];
    ushort4 o;
    o.x = f2bf(v.x * dsc); o.y = f2bf(v.y * dsc);
    o.z = f2bf(v.z * dsc); o.w = f2bf(v.w * dsc);
    ((ushort4*)xs)[i] = o;
}

// Per-(superblock, dst-quarter) LDS histogram + local rank.
// Block = (sb = blockIdx.x>>2, q = blockIdx.x&3). Packed dual 16-bit counters;
// counts per (sb,dst) <= EPB < 65536 so halves never carry.
__global__ __launch_bounds__(256) void k_hist(
        const int* __restrict__ edges, const int* __restrict__ flag,
        unsigned int* __restrict__ hist_u32,   // [nb][n/2] packed ushort pairs
        unsigned short* __restrict__ pos, long long E, int n) {
    __shared__ unsigned int bins[QBINS];       // 25 KB
    int sb = blockIdx.x >> 2, q = blockIdx.x & 3;
    int t = threadIdx.x;
    int stride = flag[0];
    long long base = (long long)sb << EPB_LOG;
    long long rem = E - base;
    int nE = (rem < (long long)EPB) ? (int)rem : EPB;
    for (int i = t; i < QBINS; i += 256) bins[i] = 0;
    __syncthreads();
    int dbase = q * QR;
    for (int i = t; i < nE; i += 256) {
        int d = edges[(E + base + i) * stride];
        unsigned int r = (unsigned int)(d - dbase);
        if (r < (unsigned int)QR) {
            unsigned int sh = (r & 1u) * 16u;
            unsigned int old = atomicAdd(&bins[r >> 1], 1u << sh);
            pos[base + i] = (unsigned short)((old >> sh) & 0xFFFFu);
        }
    }
    __syncthreads();
    int lim = n - dbase;                 // may be < QR for the last quarter
    if (lim > QR) lim = QR;
    if (lim > 0) {
        unsigned int* dstrow = hist_u32 + (size_t)sb * (n >> 1) + (dbase >> 1);
        int limu = (lim + 1) >> 1;
        for (int i = t; i < limu; i += 256) dstrow[i] = bins[i];
    }
}

// Column scan over per-superblock counts: hist[b][i] (count) -> exclusive
// offset of superblock b within node i's CSR row; cnt[i] = total.
__global__ __launch_bounds__(256) void k_colscan(
        unsigned short* __restrict__ hist, int* __restrict__ cnt, int nb, int n) {
    int i = blockIdx.x * 256 + threadIdx.x;
    if (i >= n) return;
    int run = 0;
    size_t idx = i;
    for (int b = 0; b < nb; ++b, idx += n) {
        int v = hist[idx];
        hist[idx] = (unsigned short)run;
        run += v;
    }
    cnt[i] = run;
}

// Per-block sums of cnt (8 elems/thread).
__global__ __launch_bounds__(256) void k_scan_partial(
        const int* __restrict__ cnt, int* __restrict__ bsum, int n) {
    int t = threadIdx.x;
    int idx = blockIdx.x * SCAN_TILE + t * 8;
    int s = 0;
#pragma unroll
    for (int j = 0; j < 8; ++j) {
        int i = idx + j;
        if (i < n) s += cnt[i];
    }
    for (int off = 32; off; off >>= 1) s += __shfl_down(s, off, 64);
    __shared__ int ws[4];
    if ((t & 63) == 0) ws[t >> 6] = s;
    __syncthreads();
    if (t == 0) bsum[blockIdx.x] = ws[0] + ws[1] + ws[2] + ws[3];
}

// Exclusive scan of <=64 block sums, in place, one wave.
__global__ void k_scan_tops(int* __restrict__ bsum, int nb) {
    int t = threadIdx.x;
    int w = (t < nb) ? bsum[t] : 0;
    int v = w;
    for (int off = 1; off < 64; off <<= 1) {
        int u = __shfl_up(v, off, 64);
        if (t >= off) v += u;
    }
    if (t < nb) bsum[t] = v - w;   // exclusive
}

// Apply: recompute intra-block prefix, add block offset, emit row_start & dis.
__global__ __launch_bounds__(256) void k_scan_apply(
        const int* __restrict__ cnt, const int* __restrict__ bsum,
        int* __restrict__ row_start, float* __restrict__ dis, int n) {
    int t = threadIdx.x;
    int lane = t & 63, w = t >> 6;
    int idx = blockIdx.x * SCAN_TILE + t * 8;
    int vals[8];
    int s = 0;
#pragma unroll
    for (int j = 0; j < 8; ++j) {
        int i = idx + j;
        vals[j] = (i < n) ? cnt[i] : 0;
        s += vals[j];
    }
    int inc = s;
    for (int off = 1; off < 64; off <<= 1) {
        int u = __shfl_up(inc, off, 64);
        if (lane >= off) inc += u;
    }
    __shared__ int wsum[4];
    if (lane == 63) wsum[w] = inc;
    __syncthreads();
    int woff = 0;
    for (int i = 0; i < w; ++i) woff += wsum[i];
    int ex = bsum[blockIdx.x] + woff + inc - s;  // exclusive prefix of this chunk
#pragma unroll
    for (int j = 0; j < 8; ++j) {
        int i = idx + j;
        if (i < n) {
            row_start[i] = ex;
            dis[i] = rsqrtf((float)vals[j] + 1.0f);  // +1 = self loop
            ex += vals[j];
        }
    }
    if (idx <= n && n < idx + 8) row_start[n] = ex;  // unique thread
}

// csr_src[rs[d] + boff[sb][d] + pos[e]] = s. No atomics.
__global__ void k_scatter(const int* __restrict__ edges, const int* __restrict__ flag,
                          const int* __restrict__ row_start,
                          const unsigned short* __restrict__ boff,
                          const unsigned short* __restrict__ pos,
                          int* __restrict__ csr_src, long long E, int n) {
    long long e = (long long)blockIdx.x * blockDim.x + threadIdx.x;
    if (e >= E) return;
    int stride = flag[0];
    int s = edges[e * stride];
    int d = edges[(E + e) * stride];
    int b = (int)(e >> EPB_LOG);
    int j = row_start[d] + (int)boff[(size_t)b * n + d] + (int)pos[e];
    csr_src[j] = s;
}

// ---- fallback path (only if n odd or n > 50048; never for this problem) ----
__global__ void k_count_slow(const int* __restrict__ edges, const int* __restrict__ flag,
                             int* __restrict__ cnt, int* __restrict__ posi, long long E) {
    long long e = (long long)blockIdx.x * blockDim.x + threadIdx.x;
    if (e >= E) return;
    int stride = flag[0];
    int d = edges[(E + e) * stride];
    posi[e] = atomicAdd(&cnt[d], 1);
}
__global__ void k_scatter_slow(const int* __restrict__ edges, const int* __restrict__ flag,
                               const int* __restrict__ row_start, const int* __restrict__ posi,
                               int* __restrict__ csr_src, long long E) {
    long long e = (long long)blockIdx.x * blockDim.x + threadIdx.x;
    if (e >= E) return;
    int stride = flag[0];
    int s = edges[e * stride];
    int d = edges[(E + e) * stride];
    csr_src[row_start[d] + posi[e]] = s;
}
// ---------------------------------------------------------------------------

// agg_i = dn_i * (sum_e xs[src_e] + xs_i). One wave per node; lane owns one
// uint (2 bf16 features). Per edge: 1 index load + 1 row load + 2 adds.
__global__ __launch_bounds__(256) void k_agg(
        const unsigned short* __restrict__ xs, const int* __restrict__ csr_src,
        const int* __restrict__ row_start, const float* __restrict__ dis,
        unsigned short* __restrict__ aggh, int n) {
    int wid  = (blockIdx.x * blockDim.x + threadIdx.x) >> 6;
    int lane = threadIdx.x & 63;
    if (wid >= n) return;
    int start = row_start[wid], end = row_start[wid + 1];
    unsigned int self = ((const unsigned int*)(xs + (size_t)wid * 128))[lane];
    float acc0 = bf_lo(self);
    float acc1 = bf_hi(self);
    int e = start;
    for (; e + 7 < end; e += 8) {
        int s0 = csr_src[e],     s1 = csr_src[e + 1];
        int s2 = csr_src[e + 2], s3 = csr_src[e + 3];
        int s4 = csr_src[e + 4], s5 = csr_src[e + 5];
        int s6 = csr_src[e + 6], s7 = csr_src[e + 7];
        unsigned int v0 = ((const unsigned int*)(xs + (size_t)s0 * 128))[lane];
        unsigned int v1 = ((const unsigned int*)(xs + (size_t)s1 * 128))[lane];
        unsigned int v2 = ((const unsigned int*)(xs + (size_t)s2 * 128))[lane];
        unsigned int v3 = ((const unsigned int*)(xs + (size_t)s3 * 128))[lane];
        unsigned int v4 = ((const unsigned int*)(xs + (size_t)s4 * 128))[lane];
        unsigned int v5 = ((const unsigned int*)(xs + (size_t)s5 * 128))[lane];
        unsigned int v6 = ((const unsigned int*)(xs + (size_t)s6 * 128))[lane];
        unsigned int v7 = ((const unsigned int*)(xs + (size_t)s7 * 128))[lane];
        acc0 += bf_lo(v0); acc1 += bf_hi(v0);
        acc0 += bf_lo(v1); acc1 += bf_hi(v1);
        acc0 += bf_lo(v2); acc1 += bf_hi(v2);
        acc0 += bf_lo(v3); acc1 += bf_hi(v3);
        acc0 += bf_lo(v4); acc1 += bf_hi(v4);
        acc0 += bf_lo(v5); acc1 += bf_hi(v5);
        acc0 += bf_lo(v6); acc1 += bf_hi(v6);
        acc0 += bf_lo(v7); acc1 += bf_hi(v7);
    }
    for (; e < end; ++e) {
        int s0 = csr_src[e];
        unsigned int v0 = ((const unsigned int*)(xs + (size_t)s0 * 128))[lane];
        acc0 += bf_lo(v0); acc1 += bf_hi(v0);
    }
    float dn = dis[wid];
    unsigned int pack = (unsigned int)f2bf(acc0 * dn) | ((unsigned int)f2bf(acc1 * dn) << 16);
    ((unsigned int*)(aggh + (size_t)wid * 128))[lane] = pack;
}

// MFMA GEMM: svs = dis * (relu(agg @ W1 + b1) @ W2).
__global__ __launch_bounds__(256) void k_mm(
        const unsigned short* __restrict__ aggh, const unsigned short* __restrict__ w1t,
        const float* __restrict__ b1, const float* __restrict__ W2,
        const float* __restrict__ dis, float* __restrict__ svs, int n) {
    int wave = threadIdx.x >> 6;        // 0..3
    int lane = threadIdx.x & 63;
    int m    = lane & 15;
    int quad = lane >> 4;               // 0..3
    int node0 = blockIdx.x * 64 + wave * 16;

    bf16x8 afrag[4];
    const unsigned short* arow = aggh + (size_t)(node0 + m) * 128 + quad * 8;
#pragma unroll
    for (int ks = 0; ks < 4; ++ks)
        afrag[ks] = *(const bf16x8*)(arow + ks * 32);

    float p0 = 0.f, p1 = 0.f, p2 = 0.f, p3 = 0.f;
#pragma unroll 1
    for (int t = 0; t < 16; ++t) {
        const unsigned short* brow = w1t + (size_t)(t * 16 + m) * 128 + quad * 8;
        f32x4 acc = {0.f, 0.f, 0.f, 0.f};
#pragma unroll
        for (int ks = 0; ks < 4; ++ks) {
            bf16x8 bfrag = *(const bf16x8*)(brow + ks * 32);
            acc = __builtin_amdgcn_mfma_f32_16x16x32_bf16(afrag[ks], bfrag, acc, 0, 0, 0);
        }
        int col = t * 16 + m;
        float bb = b1[col], w2 = W2[col];
        float h0 = acc[0] + bb, h1 = acc[1] + bb, h2 = acc[2] + bb, h3 = acc[3] + bb;
        p0 += (h0 > 0.f ? h0 : 0.f) * w2;
        p1 += (h1 > 0.f ? h1 : 0.f) * w2;
        p2 += (h2 > 0.f ? h2 : 0.f) * w2;
        p3 += (h3 > 0.f ? h3 : 0.f) * w2;
    }
#pragma unroll
    for (int off = 1; off < 16; off <<= 1) {
        p0 += __shfl_xor(p0, off, 64);
        p1 += __shfl_xor(p1, off, 64);
        p2 += __shfl_xor(p2, off, 64);
        p3 += __shfl_xor(p3, off, 64);
    }
    if (m == 0) {
        int nb = node0 + quad * 4;
        if (nb + 0 < n) svs[nb + 0] = p0 * dis[nb + 0];
        if (nb + 1 < n) svs[nb + 1] = p1 * dis[nb + 1];
        if (nb + 2 < n) svs[nb + 2] = p2 * dis[nb + 2];
        if (nb + 3 < n) svs[nb + 3] = p3 * dis[nb + 3];
    }
}

// out[i] = b2 + dn_i * (sum_e svs[src_e] + svs[i]); wave per node.
__global__ __launch_bounds__(256) void k_out(
        const float* __restrict__ svs, const int* __restrict__ csr_src,
        const int* __restrict__ row_start, const float* __restrict__ dis,
        const float* __restrict__ b2, float* __restrict__ out, int n) {
    int wid  = (blockIdx.x * blockDim.x + threadIdx.x) >> 6;
    int lane = threadIdx.x & 63;
    if (wid >= n) return;
    int start = row_start[wid], end = row_start[wid + 1];
    float acc = 0.f;
    for (int e = start + lane; e < end; e += 64)
        acc += svs[csr_src[e]];
    for (int off = 32; off; off >>= 1) acc += __shfl_down(acc, off, 64);
    if (lane == 0)
        out[wid] = dis[wid] * (acc + svs[wid]) + b2[0];
}

extern "C" void kernel_launch(void* const* d_in, const int* in_sizes, int n_in,
                              void* d_out, int out_size, void* d_ws, size_t ws_size,
                              hipStream_t stream) {
    const float* x  = (const float*)d_in[0];
    const int*   ei = (const int*)d_in[1];
    const float* W1 = (const float*)d_in[2];
    const float* b1 = (const float*)d_in[3];
    const float* W2 = (const float*)d_in[4];
    const float* b2 = (const float*)d_in[5];
    float* out = (float*)d_out;

    const int N = in_sizes[0] / 128;
    const long long E = in_sizes[1] / 2;
    const int nb_c = (int)((E + EPB - 1) >> EPB_LOG);   // superblocks (98)

    char* ws = (char*)d_ws;
    size_t off = 0;
    auto take = [&](size_t bytes) -> char* {
        char* p = ws + off;
        off = (off + bytes + 255) & ~(size_t)255;
        return p;
    };
    int*            flag    = (int*)take(4);
    int*            cnt     = (int*)take((size_t)N * 4);
    int*            rs      = (int*)take((size_t)(N + 1) * 4);
    float*          dis     = (float*)take((size_t)N * 4);
    float*          svs     = (float*)take((size_t)N * 4);
    int*            bsum    = (int*)take(64 * 4);
    char*           posb    = take((size_t)E * 4);        // ushort fast / int slow
    int*            csr_src = (int*)take((size_t)E * 4);
    unsigned short* xs      = (unsigned short*)take((size_t)N * 128 * 2);
    unsigned short* w1t     = (unsigned short*)take((size_t)256 * 128 * 2);
    unsigned short* aggh    = (unsigned short*)take((size_t)(N + 64) * 128 * 2);
    unsigned short* hist    = (unsigned short*)take((size_t)nb_c * (N + 2) * 2);

    int nb_n  = (N + 255) / 256;
    int nb_e  = (int)((E + 255) / 256);
    int nb_s  = (N + SCAN_TILE - 1) / SCAN_TILE;   // 25 for N=50000
    int nb_x  = (N * 32 + 255) / 256;
    int nb_mm = (N + 63) / 64;

    bool fast = ((N & 1) == 0) && (N <= MAXN_FAST);

    k_init   <<<nb_n, 256, 0, stream>>>(ei, flag, cnt, N);
    k_prep_w <<<256, 128, 0, stream>>>(W1, w1t);
    if (fast) {
        k_hist   <<<nb_c * NQ, 256, 0, stream>>>(ei, flag, (unsigned int*)hist,
                                                 (unsigned short*)posb, E, N);
        k_colscan<<<nb_n, 256, 0, stream>>>(hist, cnt, nb_c, N);
    } else {
        k_count_slow<<<nb_e, 256, 0, stream>>>(ei, flag, cnt, (int*)posb, E);
    }
    k_scan_partial<<<nb_s, 256, 0, stream>>>(cnt, bsum, N);
    k_scan_tops   <<<1, 64, 0, stream>>>(bsum, nb_s);
    k_scan_apply  <<<nb_s, 256, 0, stream>>>(cnt, bsum, rs, dis, N);
    k_prep_xs     <<<nb_x, 256, 0, stream>>>(x, dis, xs, N);
    if (fast) {
        k_scatter<<<nb_e, 256, 0, stream>>>(ei, flag, rs, hist,
                                            (const unsigned short*)posb, csr_src, E, N);
    } else {
        k_scatter_slow<<<nb_e, 256, 0, stream>>>(ei, flag, rs, (const int*)posb, csr_src, E);
    }
    k_agg<<<(N + 3) / 4, 256, 0, stream>>>(xs, csr_src, rs, dis, aggh, N);
    k_mm <<<nb_mm, 256, 0, stream>>>(aggh, w1t, b1, W2, dis, svs, N);
    k_out<<<(N + 3) / 4, 256, 0, stream>>>(svs, csr_src, rs, dis, b2, out, N);
}